// Round 1
// baseline (2759.879 us; speedup 1.0000x reference)
//
#include <hip/hip_runtime.h>
#include <hip/hip_bf16.h>

// LightGCN layer: out[dst] += w[e] * x[src]  over 1.6M edges, N=100000, D=128.
// Strategy R1: edge-parallel atomic scatter.
//   - 32 threads per edge; each lane float4-loads 4 contiguous feats of x[src],
//     scales by w[e], does 4 fp32 atomicAdds into out[dst].
//   - d_out zeroed via hipMemsetAsync on the capture stream (harness poisons
//     d_out with 0xAA before every timed replay).
// edge_index treated as int32 per harness contract (JAX x64-disabled
// canonicalizes int64 -> int32).

constexpr int D_FEAT = 128;
constexpr int LANES_PER_EDGE = D_FEAT / 4;  // 32 lanes x float4

__global__ __launch_bounds__(256) void lightgcn_scatter_kernel(
    const float* __restrict__ x,
    const float* __restrict__ w,
    const int* __restrict__ src_idx,
    const int* __restrict__ dst_idx,
    float* __restrict__ out,
    int n_edges) {
  long long tid = (long long)blockIdx.x * blockDim.x + threadIdx.x;
  int lane = (int)(tid & (LANES_PER_EDGE - 1));   // 0..31: which float4 of the row
  long long e = tid >> 5;                          // edge id
  if (e >= n_edges) return;

  int s = src_idx[e];
  int d = dst_idx[e];
  float wt = w[e];

  const float4* xrow = (const float4*)(x + (size_t)s * D_FEAT);
  float4 v = xrow[lane];

  float* o = out + (size_t)d * D_FEAT + (size_t)lane * 4;
  atomicAdd(o + 0, v.x * wt);
  atomicAdd(o + 1, v.y * wt);
  atomicAdd(o + 2, v.z * wt);
  atomicAdd(o + 3, v.w * wt);
}

extern "C" void kernel_launch(void* const* d_in, const int* in_sizes, int n_in,
                              void* d_out, int out_size, void* d_ws, size_t ws_size,
                              hipStream_t stream) {
  const float* x   = (const float*)d_in[0];
  const float* w   = (const float*)d_in[1];
  const int* eidx  = (const int*)d_in[2];
  // d_in[3] is n_nodes (scalar) — derive from out_size instead (no device read).

  int n_edges = in_sizes[1];                 // edge_weight element count = E
  const int* src = eidx;                     // edge_index[0, :]
  const int* dst = eidx + n_edges;           // edge_index[1, :]
  float* out = (float*)d_out;

  // Harness poisons d_out to 0xAA before each timed call — zero it on-stream.
  hipMemsetAsync(d_out, 0, (size_t)out_size * sizeof(float), stream);

  long long total_threads = (long long)n_edges * LANES_PER_EDGE;
  int block = 256;
  long long grid = (total_threads + block - 1) / block;
  lightgcn_scatter_kernel<<<(dim3)(unsigned)grid, block, 0, stream>>>(
      x, w, src, dst, out, n_edges);
}

// Round 2
// 505.923 us; speedup vs baseline: 5.4551x; 5.4551x over previous
//
#include <hip/hip_runtime.h>
#include <hip/hip_bf16.h>

// LightGCN layer: out[v] = sum_{(u->v)} w * x[u], N=100K, E=1.6M, D=128, fp32.
//
// R2 strategy: atomic-scatter (R1, 2760us, WRITE_SIZE=3.2GB from atomic write
// amplification) -> CSR build + gather. Phases, all on `stream`:
//   0. memsetAsync cnt=0 (400KB in d_ws)
//   1. histogram: cnt[dst[e]]++  (int atomics, L2-resident)
//   2. single-block scan -> off[0..N], zeroes cnt for reuse as cursor
//   3. build CSR: pos = off[d] + atomicAdd(cur[d],1); csr_src/csr_w[pos]
//   4. gather: 32 lanes x float4 per node, register acc, ONE write per output
// No fp atomics anywhere. Falls back to R1 path if ws_size too small.

constexpr int D_FEAT = 128;

// ---------------- fallback (R1) ----------------
__global__ __launch_bounds__(256) void scatter_atomic_kernel(
    const float* __restrict__ x, const float* __restrict__ w,
    const int* __restrict__ src_idx, const int* __restrict__ dst_idx,
    float* __restrict__ out, int n_edges) {
  long long tid = (long long)blockIdx.x * blockDim.x + threadIdx.x;
  int lane = (int)(tid & 31);
  long long e = tid >> 5;
  if (e >= n_edges) return;
  int s = src_idx[e];
  int d = dst_idx[e];
  float wt = w[e];
  float4 v = ((const float4*)(x + (size_t)s * D_FEAT))[lane];
  float* o = out + (size_t)d * D_FEAT + (size_t)lane * 4;
  atomicAdd(o + 0, v.x * wt);
  atomicAdd(o + 1, v.y * wt);
  atomicAdd(o + 2, v.z * wt);
  atomicAdd(o + 3, v.w * wt);
}

// ---------------- phase 1: histogram ----------------
__global__ __launch_bounds__(256) void hist_kernel(
    const int* __restrict__ dst, int* __restrict__ cnt, int n_edges) {
  int i = blockIdx.x * blockDim.x + threadIdx.x;
  if (i < n_edges) atomicAdd(&cnt[dst[i]], 1);
}

// ---------------- phase 2: single-block scan ----------------
// 1024 threads, tiles of 1024. Inclusive shfl scan per wave (64), then scan of
// 16 wave sums by wave 0, then carry across tiles. Also zeroes cnt (cursor
// reuse in phase 3) and writes off[n].
__global__ __launch_bounds__(1024) void scan_kernel(
    int* __restrict__ cnt, int* __restrict__ off, int n) {
  __shared__ int wsum[16];
  __shared__ int woff[16];
  __shared__ int carry_s;
  __shared__ int tile_total_s;
  const int tid = threadIdx.x;
  const int lane = tid & 63;
  const int wid = tid >> 6;
  if (tid == 0) carry_s = 0;
  __syncthreads();

  for (int base = 0; base < n; base += 1024) {
    int i = base + tid;
    int c = (i < n) ? cnt[i] : 0;
    // wave-inclusive scan
    int v = c;
    #pragma unroll
    for (int o = 1; o < 64; o <<= 1) {
      int t = __shfl_up(v, o, 64);
      if (lane >= o) v += t;
    }
    if (lane == 63) wsum[wid] = v;
    __syncthreads();
    if (wid == 0 && lane < 16) {
      int s = wsum[lane];
      #pragma unroll
      for (int o = 1; o < 16; o <<= 1) {
        int t = __shfl_up(s, o, 64);
        if (lane >= o) s += t;
      }
      woff[lane] = s - wsum[lane];   // exclusive wave offset
      if (lane == 15) tile_total_s = s;
    }
    __syncthreads();
    if (i < n) {
      off[i] = carry_s + woff[wid] + (v - c);  // exclusive global prefix
      cnt[i] = 0;                               // reset for cursor use
    }
    __syncthreads();
    if (tid == 0) carry_s += tile_total_s;
    __syncthreads();
  }
  if (threadIdx.x == 0) off[n] = carry_s;
}

// ---------------- phase 3: build CSR ----------------
__global__ __launch_bounds__(256) void build_csr_kernel(
    const int* __restrict__ src, const int* __restrict__ dst,
    const float* __restrict__ w, const int* __restrict__ off,
    int* __restrict__ cur, int* __restrict__ csr_src,
    float* __restrict__ csr_w, int n_edges) {
  int i = blockIdx.x * blockDim.x + threadIdx.x;
  if (i >= n_edges) return;
  int d = dst[i];
  int pos = off[d] + atomicAdd(&cur[d], 1);
  csr_src[pos] = src[i];
  csr_w[pos] = w[i];
}

// ---------------- phase 4: gather ----------------
// 8 nodes per 256-block; 32 lanes x float4 per node; register accumulate.
__global__ __launch_bounds__(256) void gather_kernel(
    const float* __restrict__ x, const int* __restrict__ off,
    const int* __restrict__ csr_src, const float* __restrict__ csr_w,
    float* __restrict__ out, int n_nodes) {
  int node = blockIdx.x * 8 + (threadIdx.x >> 5);
  int f = threadIdx.x & 31;
  if (node >= n_nodes) return;
  int beg = off[node];
  int end = off[node + 1];
  const float4* X = (const float4*)x;
  float4 acc = make_float4(0.f, 0.f, 0.f, 0.f);
  for (int j = beg; j < end; ++j) {
    int s = csr_src[j];       // wave-broadcast (2 distinct addrs per wave)
    float wt = csr_w[j];
    float4 v = X[(size_t)s * 32 + f];
    acc.x += wt * v.x;
    acc.y += wt * v.y;
    acc.z += wt * v.z;
    acc.w += wt * v.w;
  }
  ((float4*)out)[(size_t)node * 32 + f] = acc;
}

extern "C" void kernel_launch(void* const* d_in, const int* in_sizes, int n_in,
                              void* d_out, int out_size, void* d_ws, size_t ws_size,
                              hipStream_t stream) {
  const float* x  = (const float*)d_in[0];
  const float* w  = (const float*)d_in[1];
  const int* eidx = (const int*)d_in[2];

  const int n_edges = in_sizes[1];           // E (edge_weight count)
  const int n_nodes = out_size / D_FEAT;     // N
  const int* src = eidx;                     // edge_index[0, :]
  const int* dst = eidx + n_edges;           // edge_index[1, :]
  float* out = (float*)d_out;

  // workspace layout
  size_t need = (size_t)(n_nodes + 1) * 4 + (size_t)n_nodes * 4 +
                (size_t)n_edges * 8;
  if (ws_size < need) {
    // fallback: R1 atomic path
    hipMemsetAsync(d_out, 0, (size_t)out_size * sizeof(float), stream);
    long long total_threads = (long long)n_edges * 32;
    long long grid = (total_threads + 255) / 256;
    scatter_atomic_kernel<<<(dim3)(unsigned)grid, 256, 0, stream>>>(
        x, w, src, dst, out, n_edges);
    return;
  }

  int* off_arr  = (int*)d_ws;                     // N+1
  int* cnt      = off_arr + (n_nodes + 1);        // N (histogram, then cursor)
  int* csr_src  = cnt + n_nodes;                  // E
  float* csr_w  = (float*)(csr_src + n_edges);    // E

  hipMemsetAsync(cnt, 0, (size_t)n_nodes * sizeof(int), stream);

  int eblocks = (n_edges + 255) / 256;
  hist_kernel<<<eblocks, 256, 0, stream>>>(dst, cnt, n_edges);
  scan_kernel<<<1, 1024, 0, stream>>>(cnt, off_arr, n_nodes);
  build_csr_kernel<<<eblocks, 256, 0, stream>>>(src, dst, w, off_arr, cnt,
                                                csr_src, csr_w, n_edges);
  int gblocks = (n_nodes + 7) / 8;
  gather_kernel<<<gblocks, 256, 0, stream>>>(x, off_arr, csr_src, csr_w, out,
                                             n_nodes);
}

// Round 3
// 378.911 us; speedup vs baseline: 7.2837x; 1.3352x over previous
//
#include <hip/hip_runtime.h>
#include <hip/hip_bf16.h>

// LightGCN layer: out[v] = sum_{(u->v)} w * x[u], N=100K, E=1.6M, D=128, fp32.
//
// R3: R2 (506us) spent ~378us on CSR build, dominated by the single-block
// scan (~150us est). Changes:
//   - 3-pass multi-block scan (chunk sums -> scan sums -> rescan+write)
//   - CSR packed as uint2{src, w_bits}: 1 random 8B store/edge, 1 load/edge
//   - gather unrolled x2 (dual acc) to hide x-row load latency
//   - histogram int4 loads
// Phases on `stream`: memset cnt -> hist -> scanA/B/C (C zeroes cnt for reuse
// as cursor) -> build_csr -> gather. No fp atomics anywhere.

constexpr int D_FEAT = 128;
constexpr int SCAN_CHUNK = 512;   // elements per scan block (256 thr x int2)

// ---------------- fallback (R1) ----------------
__global__ __launch_bounds__(256) void scatter_atomic_kernel(
    const float* __restrict__ x, const float* __restrict__ w,
    const int* __restrict__ src_idx, const int* __restrict__ dst_idx,
    float* __restrict__ out, int n_edges) {
  long long tid = (long long)blockIdx.x * blockDim.x + threadIdx.x;
  int lane = (int)(tid & 31);
  long long e = tid >> 5;
  if (e >= n_edges) return;
  int s = src_idx[e];
  int d = dst_idx[e];
  float wt = w[e];
  float4 v = ((const float4*)(x + (size_t)s * D_FEAT))[lane];
  float* o = out + (size_t)d * D_FEAT + (size_t)lane * 4;
  atomicAdd(o + 0, v.x * wt);
  atomicAdd(o + 1, v.y * wt);
  atomicAdd(o + 2, v.z * wt);
  atomicAdd(o + 3, v.w * wt);
}

// ---------------- phase 1: histogram (int4 dst loads) ----------------
__global__ __launch_bounds__(256) void hist_kernel(
    const int* __restrict__ dst, int* __restrict__ cnt, int n_edges) {
  int i = blockIdx.x * blockDim.x + threadIdx.x;
  int base = i * 4;
  if (base + 3 < n_edges) {
    int4 d = ((const int4*)dst)[i];
    atomicAdd(&cnt[d.x], 1);
    atomicAdd(&cnt[d.y], 1);
    atomicAdd(&cnt[d.z], 1);
    atomicAdd(&cnt[d.w], 1);
  } else {
    for (int k = base; k < n_edges; ++k) atomicAdd(&cnt[dst[k]], 1);
  }
}

// ---------------- block exclusive scan helper (256 threads) ----------------
__device__ __forceinline__ int block_excl_scan_256(int v, int* wsum) {
  const int lane = threadIdx.x & 63;
  const int wid = threadIdx.x >> 6;
  int inc = v;
  #pragma unroll
  for (int o = 1; o < 64; o <<= 1) {
    int t = __shfl_up(inc, o, 64);
    if (lane >= o) inc += t;
  }
  if (lane == 63) wsum[wid] = inc;
  __syncthreads();
  if (threadIdx.x == 0) {
    int a = 0;
    #pragma unroll
    for (int k = 0; k < 4; ++k) { int t = wsum[k]; wsum[k] = a; a += t; }
  }
  __syncthreads();
  return wsum[wid] + inc - v;   // exclusive prefix
}

// ---------------- phase 2a: per-chunk sums ----------------
__global__ __launch_bounds__(256) void chunk_sum_kernel(
    const int* __restrict__ cnt, int* __restrict__ bsum, int n) {
  __shared__ int wsum[4];
  int t = threadIdx.x;
  int i = blockIdx.x * SCAN_CHUNK + 2 * t;
  int2 c = make_int2(0, 0);
  if (i + 1 < n) c = ((const int2*)cnt)[blockIdx.x * 256 + t];
  else if (i < n) c.x = cnt[i];
  int s = c.x + c.y;
  // block reduce via wave shfl + LDS
  const int lane = t & 63;
  const int wid = t >> 6;
  #pragma unroll
  for (int o = 32; o >= 1; o >>= 1) s += __shfl_down(s, o, 64);
  if (lane == 0) wsum[wid] = s;
  __syncthreads();
  if (t == 0) bsum[blockIdx.x] = wsum[0] + wsum[1] + wsum[2] + wsum[3];
}

// ---------------- phase 2b: scan chunk sums (1 block, nchunks<=256) --------
__global__ __launch_bounds__(256) void scan_bsum_kernel(
    int* __restrict__ bsum, int nchunks, int* __restrict__ off, int n,
    int total) {
  __shared__ int wsum[4];
  int t = threadIdx.x;
  int v = (t < nchunks) ? bsum[t] : 0;
  int ex = block_excl_scan_256(v, wsum);
  if (t < nchunks) bsum[t] = ex;
  if (t == 0) off[n] = total;   // sum of hist == E (all dst in [0,N))
}

// ---------------- phase 2c: rescan chunks, write off, zero cnt -------------
__global__ __launch_bounds__(256) void scan_write_kernel(
    int* __restrict__ cnt, const int* __restrict__ bsum, int* __restrict__ off,
    int n) {
  __shared__ int wsum[4];
  int t = threadIdx.x;
  int i = blockIdx.x * SCAN_CHUNK + 2 * t;
  int2 c = make_int2(0, 0);
  if (i + 1 < n) c = ((const int2*)cnt)[blockIdx.x * 256 + t];
  else if (i < n) c.x = cnt[i];
  int s = c.x + c.y;
  int ex = block_excl_scan_256(s, wsum) + bsum[blockIdx.x];
  if (i + 1 < n) {
    ((int2*)off)[blockIdx.x * 256 + t] = make_int2(ex, ex + c.x);
    ((int2*)cnt)[blockIdx.x * 256 + t] = make_int2(0, 0);
  } else if (i < n) {
    off[i] = ex;
    cnt[i] = 0;
  }
}

// ---------------- phase 3: build packed CSR ----------------
__global__ __launch_bounds__(256) void build_csr_kernel(
    const int* __restrict__ src, const int* __restrict__ dst,
    const float* __restrict__ w, const int* __restrict__ off,
    int* __restrict__ cur, uint2* __restrict__ csr, int n_edges) {
  int i = blockIdx.x * blockDim.x + threadIdx.x;
  if (i >= n_edges) return;
  int d = dst[i];
  int pos = off[d] + atomicAdd(&cur[d], 1);
  csr[pos] = make_uint2((unsigned)src[i], __float_as_uint(w[i]));
}

// ---------------- phase 4: gather (unroll x2) ----------------
__global__ __launch_bounds__(256) void gather_kernel(
    const float* __restrict__ x, const int* __restrict__ off,
    const uint2* __restrict__ csr, float* __restrict__ out, int n_nodes) {
  int node = blockIdx.x * 8 + (threadIdx.x >> 5);
  int f = threadIdx.x & 31;
  if (node >= n_nodes) return;
  int beg = off[node];
  int end = off[node + 1];
  const float4* X = (const float4*)x;
  float4 a0 = make_float4(0.f, 0.f, 0.f, 0.f);
  float4 a1 = make_float4(0.f, 0.f, 0.f, 0.f);
  int j = beg;
  for (; j + 1 < end; j += 2) {
    uint2 e0 = csr[j];
    uint2 e1 = csr[j + 1];
    float4 v0 = X[(size_t)e0.x * 32 + f];
    float4 v1 = X[(size_t)e1.x * 32 + f];
    float w0 = __uint_as_float(e0.y);
    float w1 = __uint_as_float(e1.y);
    a0.x += w0 * v0.x; a0.y += w0 * v0.y; a0.z += w0 * v0.z; a0.w += w0 * v0.w;
    a1.x += w1 * v1.x; a1.y += w1 * v1.y; a1.z += w1 * v1.z; a1.w += w1 * v1.w;
  }
  if (j < end) {
    uint2 e0 = csr[j];
    float4 v0 = X[(size_t)e0.x * 32 + f];
    float w0 = __uint_as_float(e0.y);
    a0.x += w0 * v0.x; a0.y += w0 * v0.y; a0.z += w0 * v0.z; a0.w += w0 * v0.w;
  }
  a0.x += a1.x; a0.y += a1.y; a0.z += a1.z; a0.w += a1.w;
  ((float4*)out)[(size_t)node * 32 + f] = a0;
}

extern "C" void kernel_launch(void* const* d_in, const int* in_sizes, int n_in,
                              void* d_out, int out_size, void* d_ws, size_t ws_size,
                              hipStream_t stream) {
  const float* x  = (const float*)d_in[0];
  const float* w  = (const float*)d_in[1];
  const int* eidx = (const int*)d_in[2];

  const int n_edges = in_sizes[1];           // E
  const int n_nodes = out_size / D_FEAT;     // N
  const int* src = eidx;
  const int* dst = eidx + n_edges;
  float* out = (float*)d_out;

  const int nchunks = (n_nodes + SCAN_CHUNK - 1) / SCAN_CHUNK;   // 196 @100K

  // workspace layout (keep 8B alignment for int2/uint2 views):
  //   off:  N+2 ints (N+1 used, +1 pad for alignment)
  //   cnt:  N ints (histogram, then cursor)
  //   bsum: nchunks ints (rounded to even)
  //   csr:  E uint2
  const int n_off = n_nodes + 2;
  const int n_bsum = (nchunks + 1) & ~1;
  size_t need = ((size_t)n_off + n_nodes + n_bsum) * 4 + (size_t)n_edges * 8;
  if (ws_size < need || nchunks > 256) {
    hipMemsetAsync(d_out, 0, (size_t)out_size * sizeof(float), stream);
    long long total_threads = (long long)n_edges * 32;
    long long grid = (total_threads + 255) / 256;
    scatter_atomic_kernel<<<(dim3)(unsigned)grid, 256, 0, stream>>>(
        x, w, src, dst, out, n_edges);
    return;
  }

  int* off_arr = (int*)d_ws;                 // N+2
  int* cnt     = off_arr + n_off;            // N
  int* bsum    = cnt + n_nodes;              // n_bsum
  uint2* csr   = (uint2*)(bsum + n_bsum);    // E

  hipMemsetAsync(cnt, 0, (size_t)n_nodes * sizeof(int), stream);

  int hblocks = ((n_edges + 3) / 4 + 255) / 256;
  hist_kernel<<<hblocks, 256, 0, stream>>>(dst, cnt, n_edges);
  chunk_sum_kernel<<<nchunks, 256, 0, stream>>>(cnt, bsum, n_nodes);
  scan_bsum_kernel<<<1, 256, 0, stream>>>(bsum, nchunks, off_arr, n_nodes,
                                          n_edges);
  scan_write_kernel<<<nchunks, 256, 0, stream>>>(cnt, bsum, off_arr, n_nodes);
  int eblocks = (n_edges + 255) / 256;
  build_csr_kernel<<<eblocks, 256, 0, stream>>>(src, dst, w, off_arr, cnt,
                                                csr, n_edges);
  int gblocks = (n_nodes + 7) / 8;
  gather_kernel<<<gblocks, 256, 0, stream>>>(x, off_arr, csr, out, n_nodes);
}